// Round 1
// baseline (728.610 us; speedup 1.0000x reference)
//
#include <hip/hip_runtime.h>

// QuantSoftmax: per-tensor int8 quant + integer-domain softmax.
// x: (8,12,1024,1024) f32. Pass 1: global absmax. Pass 2: one wave per
// 1024-elem row (16 elems/lane), shuffle-only reductions.

__device__ __forceinline__ float waveMax(float v) {
#pragma unroll
    for (int m = 32; m >= 1; m >>= 1)
        v = fmaxf(v, __shfl_xor(v, m, 64));
    return v;
}

__device__ __forceinline__ unsigned waveSum(unsigned v) {
#pragma unroll
    for (int m = 32; m >= 1; m >>= 1)
        v += __shfl_xor(v, m, 64);
    return v;
}

__global__ __launch_bounds__(256) void absmax_k(const float4* __restrict__ x, int n4,
                                                unsigned* __restrict__ ws) {
    int tid = blockIdx.x * blockDim.x + threadIdx.x;
    int stride = gridDim.x * blockDim.x;
    float m = 0.0f;
    for (int i = tid; i < n4; i += stride) {
        float4 v = x[i];
        m = fmaxf(fmaxf(fabsf(v.x), fabsf(v.y)),
                  fmaxf(fmaxf(fabsf(v.z), fabsf(v.w)), m));
    }
    m = waveMax(m);
    __shared__ float sm[4];
    int lane = threadIdx.x & 63;
    int wid = threadIdx.x >> 6;
    if (lane == 0) sm[wid] = m;
    __syncthreads();
    if (threadIdx.x == 0) {
        float b = fmaxf(fmaxf(sm[0], sm[1]), fmaxf(sm[2], sm[3]));
        // abs values are non-negative -> IEEE bits are monotone as unsigned
        atomicMax(ws, __float_as_uint(b));
    }
}

__global__ __launch_bounds__(256) void qsm_k(const float* __restrict__ x,
                                             float* __restrict__ out,
                                             const unsigned* __restrict__ ws,
                                             int nrows) {
    const int wid  = threadIdx.x >> 6;
    const int lane = threadIdx.x & 63;
    const int row  = (blockIdx.x << 2) + wid;
    if (row >= nrows) return;

    const float absmax = __uint_as_float(*ws);
    const float scale  = absmax / 127.0f;          // IEEE div, matches jnp
    const float x0     = floorf(-1.0f / scale);    // negative integer
    const float clampv = 15.0f * x0;               // CONST_N * x0_int

    const size_t base = (size_t)row * 1024 + (size_t)(lane << 2);
    const float* xr = x + base;

    float vals[16];
    *(float4*)(vals + 0)  = *(const float4*)(xr + 0);
    *(float4*)(vals + 4)  = *(const float4*)(xr + 256);
    *(float4*)(vals + 8)  = *(const float4*)(xr + 512);
    *(float4*)(vals + 12) = *(const float4*)(xr + 768);

    // quantize + row max
    float mx = -3.4e38f;
#pragma unroll
    for (int j = 0; j < 16; ++j) {
        float q = rintf(vals[j] / scale);          // IEEE div + rne, matches jnp.round
        q = fminf(fmaxf(q, -128.0f), 127.0f);
        vals[j] = q;
        mx = fmaxf(mx, q);
    }
    mx = waveMax(mx);

    // integer exp + exact integer row sum
    unsigned lsum = 0;
#pragma unroll
    for (int j = 0; j < 16; ++j) {
        float xi = vals[j] - mx;                               // [-255, 0], exact int
        xi = xi + floorf(xi * 0.5f) - floorf(xi * 0.0625f);    // /2, /16 exact
        xi = fmaxf(xi, clampv);
        float q = floorf(xi / x0);                             // 0..15
        float r = xi - x0 * q;                                 // exact small int
        int qi = (int)q;
        float e = r * 0.5f - x0;
        float two = __uint_as_float((unsigned)(127 + 15 - qi) << 23); // exp2(15-q)
        e = fmaxf(floorf(e * two), 0.0f);
        vals[j] = e;
        lsum += (unsigned)e;                                   // exact integer sum
    }
    unsigned s = waveSum(lsum);

    // INT32_MAX as f32 == 2^31 exactly (matches jnp weak-type promotion)
    float sumf   = fminf((float)s, 2147483648.0f);
    float factor = floorf(2147483648.0f / sumf);

    const float INV16 = 1.0f / 65536.0f;   // exact pow2: identical to /2^16
    const float G     = 1.0f / 32768.0f;   // G_VALUE = 2^-15
#pragma unroll
    for (int j = 0; j < 16; ++j) {
        float p = vals[j] * factor;        // fp32 round BEFORE floor, like jnp
        vals[j] = floorf(p * INV16) * G;
    }

    float* orow = out + base;
    *(float4*)(orow + 0)   = *(const float4*)(vals + 0);
    *(float4*)(orow + 256) = *(const float4*)(vals + 4);
    *(float4*)(orow + 512) = *(const float4*)(vals + 8);
    *(float4*)(orow + 768) = *(const float4*)(vals + 12);
}

extern "C" void kernel_launch(void* const* d_in, const int* in_sizes, int n_in,
                              void* d_out, int out_size, void* d_ws, size_t ws_size,
                              hipStream_t stream) {
    const float* x = (const float*)d_in[0];
    float* out = (float*)d_out;
    unsigned* ws = (unsigned*)d_ws;
    const int n = in_sizes[0];          // 100663296
    const int n4 = n >> 2;
    const int nrows = n >> 10;          // 98304 rows of 1024

    hipMemsetAsync(ws, 0, sizeof(unsigned), stream);
    absmax_k<<<2048, 256, 0, stream>>>((const float4*)x, n4, ws);
    qsm_k<<<nrows / 4, 256, 0, stream>>>(x, out, ws, nrows);
}

// Round 2
// 705.425 us; speedup vs baseline: 1.0329x; 1.0329x over previous
//
#include <hip/hip_runtime.h>

// QuantSoftmax: per-tensor int8 quant + integer-domain softmax.
// x: (8,12,1024,1024) f32.
// Pass 1: global absmax (streams x; L3 ends holding x's tail).
// Pass 2: one wave per 1024-elem row, rows processed in DESCENDING order so
//         the first reads hit the L3-resident tail left by pass 1.
//         exp_int is a pure function of d = rowmax - q (d in [0,255]) given
//         the global scale -> 256-entry LDS table built once per block with
//         the exact reference fp32 op sequence.

__device__ __forceinline__ float waveMax(float v) {
#pragma unroll
    for (int m = 32; m >= 1; m >>= 1)
        v = fmaxf(v, __shfl_xor(v, m, 64));
    return v;
}

__device__ __forceinline__ unsigned waveSum(unsigned v) {
#pragma unroll
    for (int m = 32; m >= 1; m >>= 1)
        v += __shfl_xor(v, m, 64);
    return v;
}

__global__ __launch_bounds__(256) void absmax_k(const float4* __restrict__ x, int n4,
                                                unsigned* __restrict__ ws) {
    int tid = blockIdx.x * blockDim.x + threadIdx.x;
    int stride = gridDim.x * blockDim.x;
    float m = 0.0f;
    for (int i = tid; i < n4; i += stride) {
        float4 v = x[i];
        m = fmaxf(fmaxf(fabsf(v.x), fabsf(v.y)),
                  fmaxf(fmaxf(fabsf(v.z), fabsf(v.w)), m));
    }
    m = waveMax(m);
    __shared__ float sm[4];
    int lane = threadIdx.x & 63;
    int wid = threadIdx.x >> 6;
    if (lane == 0) sm[wid] = m;
    __syncthreads();
    if (threadIdx.x == 0) {
        float b = fmaxf(fmaxf(sm[0], sm[1]), fmaxf(sm[2], sm[3]));
        // abs values are non-negative -> IEEE bits monotone as unsigned
        atomicMax(ws, __float_as_uint(b));
    }
}

__global__ __launch_bounds__(256) void qsm_k(const float* __restrict__ x,
                                             float* __restrict__ out,
                                             const unsigned* __restrict__ ws,
                                             int nrows) {
    const float absmax = __uint_as_float(*ws);
    const float scale  = absmax / 127.0f;          // IEEE div, matches jnp
    const float x0     = floorf(-1.0f / scale);    // negative integer
    const float clampv = 15.0f * x0;               // CONST_N * x0_int (exact)

    // --- build exp_int table: entry d corresponds to x_int - rowmax = -d ---
    // Exact same fp32 op sequence as the reference's elementwise path.
    __shared__ float tbl[256];
    {
        const int t = threadIdx.x;                 // 256 threads, 256 entries
        float xi = -(float)t;
        xi = xi + floorf(xi * 0.5f) - floorf(xi * 0.0625f);  // /2, /16 exact
        xi = fmaxf(xi, clampv);
        float q = floorf(xi / x0);                 // 0..15
        float r = xi - x0 * q;                     // exact small int
        float e = r * 0.5f - x0;                   // exact multiple of 0.5
        float two = __uint_as_float((unsigned)(127 + 15 - (int)q) << 23); // exp2(15-q)
        tbl[t] = fmaxf(floorf(e * two), 0.0f);     // exact integer <= ~2^21
    }
    __syncthreads();

    const int wid  = threadIdx.x >> 6;
    const int lane = threadIdx.x & 63;
    // DESCENDING rows: block 0 touches the tail of x (L3-hot from pass 1)
    const int row  = nrows - 1 - ((blockIdx.x << 2) + wid);

    const size_t base = (size_t)row * 1024 + (size_t)(lane << 2);
    const float* xr = x + base;

    float vals[16];
    *(float4*)(vals + 0)  = *(const float4*)(xr + 0);
    *(float4*)(vals + 4)  = *(const float4*)(xr + 256);
    *(float4*)(vals + 8)  = *(const float4*)(xr + 512);
    *(float4*)(vals + 12) = *(const float4*)(xr + 768);

    // quantize + row max
    float mx = -3.4e38f;
#pragma unroll
    for (int j = 0; j < 16; ++j) {
        float q = rintf(vals[j] / scale);          // IEEE div + rne = jnp.round
        q = fminf(fmaxf(q, -128.0f), 127.0f);
        vals[j] = q;
        mx = fmaxf(mx, q);
    }
    mx = waveMax(mx);

    // exp_int via table; per-lane fp32 partial sum is exact (<= 12.3M < 2^24)
    float lsumf = 0.0f;
#pragma unroll
    for (int j = 0; j < 16; ++j) {
        int d = (int)(mx - vals[j]);               // 0..255 exact
        float e = tbl[d];
        vals[j] = e;
        lsumf += e;
    }
    unsigned s = waveSum((unsigned)lsumf);

    // INT32_MAX as f32 == 2^31 exactly (jnp weak-type promotion)
    float sumf   = fminf((float)s, 2147483648.0f);
    float factor = floorf(2147483648.0f / sumf);

    const float INV16 = 1.0f / 65536.0f;   // exact pow2 == /2^16
    const float G     = 1.0f / 32768.0f;   // G_VALUE = 2^-15
#pragma unroll
    for (int j = 0; j < 16; ++j) {
        float p = vals[j] * factor;        // fp32 round BEFORE floor, like jnp
        vals[j] = floorf(p * INV16) * G;
    }

    float* orow = out + base;
    *(float4*)(orow + 0)   = *(const float4*)(vals + 0);
    *(float4*)(orow + 256) = *(const float4*)(vals + 4);
    *(float4*)(orow + 512) = *(const float4*)(vals + 8);
    *(float4*)(orow + 768) = *(const float4*)(vals + 12);
}

extern "C" void kernel_launch(void* const* d_in, const int* in_sizes, int n_in,
                              void* d_out, int out_size, void* d_ws, size_t ws_size,
                              hipStream_t stream) {
    const float* x = (const float*)d_in[0];
    float* out = (float*)d_out;
    unsigned* ws = (unsigned*)d_ws;
    const int n = in_sizes[0];          // 100663296
    const int n4 = n >> 2;
    const int nrows = n >> 10;          // 98304 rows of 1024

    hipMemsetAsync(ws, 0, sizeof(unsigned), stream);
    absmax_k<<<2048, 256, 0, stream>>>((const float4*)x, n4, ws);
    qsm_k<<<nrows / 4, 256, 0, stream>>>(x, out, ws, nrows);
}

// Round 4
// 697.942 us; speedup vs baseline: 1.0439x; 1.0107x over previous
//
#include <hip/hip_runtime.h>

// QuantSoftmax: per-tensor int8 quant + integer-domain softmax.
// x: (8,12,1024,1024) f32.
// Pass 1: global absmax (streams x forward; L3 ends holding x's tail).
// Pass 2: one wave per 1024-elem row, rows DESCENDING so first reads hit the
//         L3-resident tail. out is written with NONTEMPORAL stores so the
//         402 MB of writes don't evict x from L3 mid-pass.
//         exp_int is a pure function of d = rowmax - q (d in [0,255]) given
//         the global scale -> 256-entry LDS table, exact reference fp32 ops.

typedef float vf4 __attribute__((ext_vector_type(4)));  // clang vector: ok for nontemporal builtins

__device__ __forceinline__ float waveMax(float v) {
#pragma unroll
    for (int m = 32; m >= 1; m >>= 1)
        v = fmaxf(v, __shfl_xor(v, m, 64));
    return v;
}

__device__ __forceinline__ unsigned waveSum(unsigned v) {
#pragma unroll
    for (int m = 32; m >= 1; m >>= 1)
        v += __shfl_xor(v, m, 64);
    return v;
}

__global__ __launch_bounds__(256) void absmax_k(const vf4* __restrict__ x, int n4,
                                                unsigned* __restrict__ ws) {
    int tid = blockIdx.x * blockDim.x + threadIdx.x;
    int stride = gridDim.x * blockDim.x;
    float m = 0.0f;
    for (int i = tid; i < n4; i += stride) {
        vf4 v = x[i];
        m = fmaxf(fmaxf(fabsf(v.x), fabsf(v.y)),
                  fmaxf(fmaxf(fabsf(v.z), fabsf(v.w)), m));
    }
    m = waveMax(m);
    __shared__ float sm[4];
    int lane = threadIdx.x & 63;
    int wid = threadIdx.x >> 6;
    if (lane == 0) sm[wid] = m;
    __syncthreads();
    if (threadIdx.x == 0) {
        float b = fmaxf(fmaxf(sm[0], sm[1]), fmaxf(sm[2], sm[3]));
        // abs values non-negative -> IEEE bits monotone as unsigned
        atomicMax(ws, __float_as_uint(b));
    }
}

__global__ __launch_bounds__(256) void qsm_k(const float* __restrict__ x,
                                             float* __restrict__ out,
                                             const unsigned* __restrict__ ws,
                                             int nrows) {
    const float absmax = __uint_as_float(*ws);
    const float scale  = absmax / 127.0f;          // IEEE div, matches jnp
    const float x0     = floorf(-1.0f / scale);    // negative integer
    const float clampv = 15.0f * x0;               // CONST_N * x0_int (exact)

    // --- exp_int table: entry d corresponds to x_int - rowmax = -d ---
    __shared__ float tbl[256];
    {
        const int t = threadIdx.x;
        float xi = -(float)t;
        xi = xi + floorf(xi * 0.5f) - floorf(xi * 0.0625f);  // /2, /16 exact
        xi = fmaxf(xi, clampv);
        float q = floorf(xi / x0);                 // 0..15
        float r = xi - x0 * q;                     // exact small int
        float e = r * 0.5f - x0;                   // exact multiple of 0.5
        float two = __uint_as_float((unsigned)(127 + 15 - (int)q) << 23); // exp2(15-q)
        tbl[t] = fmaxf(floorf(e * two), 0.0f);     // exact integer <= ~2^21
    }
    __syncthreads();

    const int wid  = threadIdx.x >> 6;
    const int lane = threadIdx.x & 63;
    // DESCENDING rows: block 0 touches the tail of x (L3-hot from pass 1)
    const int row  = nrows - 1 - ((blockIdx.x << 2) + wid);

    const size_t base = (size_t)row * 1024 + (size_t)(lane << 2);
    const float* xr = x + base;

    float vals[16];
    *(vf4*)(vals + 0)  = *(const vf4*)(xr + 0);
    *(vf4*)(vals + 4)  = *(const vf4*)(xr + 256);
    *(vf4*)(vals + 8)  = *(const vf4*)(xr + 512);
    *(vf4*)(vals + 12) = *(const vf4*)(xr + 768);

    // quantize + row max
    float mx = -3.4e38f;
#pragma unroll
    for (int j = 0; j < 16; ++j) {
        float q = rintf(vals[j] / scale);          // IEEE div + rne = jnp.round
        q = fminf(fmaxf(q, -128.0f), 127.0f);
        vals[j] = q;
        mx = fmaxf(mx, q);
    }
    mx = waveMax(mx);

    // exp_int via table; per-lane fp32 partial sum exact (<= 12.3M < 2^24)
    float lsumf = 0.0f;
#pragma unroll
    for (int j = 0; j < 16; ++j) {
        int d = (int)(mx - vals[j]);               // 0..255 exact
        float e = tbl[d];
        vals[j] = e;
        lsumf += e;
    }
    unsigned s = waveSum((unsigned)lsumf);

    // INT32_MAX as f32 == 2^31 exactly (jnp weak-type promotion)
    float sumf   = fminf((float)s, 2147483648.0f);
    float factor = floorf(2147483648.0f / sumf);

    const float INV16 = 1.0f / 65536.0f;   // exact pow2 == /2^16
    const float G     = 1.0f / 32768.0f;   // G_VALUE = 2^-15
#pragma unroll
    for (int j = 0; j < 16; ++j) {
        float p = vals[j] * factor;        // fp32 round BEFORE floor, like jnp
        vals[j] = floorf(p * INV16) * G;
    }

    // Nontemporal stores: stream out to HBM, keep L3 for x re-reads
    float* orow = out + base;
    __builtin_nontemporal_store(*(vf4*)(vals + 0),  (vf4*)(orow + 0));
    __builtin_nontemporal_store(*(vf4*)(vals + 4),  (vf4*)(orow + 256));
    __builtin_nontemporal_store(*(vf4*)(vals + 8),  (vf4*)(orow + 512));
    __builtin_nontemporal_store(*(vf4*)(vals + 12), (vf4*)(orow + 768));
}

extern "C" void kernel_launch(void* const* d_in, const int* in_sizes, int n_in,
                              void* d_out, int out_size, void* d_ws, size_t ws_size,
                              hipStream_t stream) {
    const float* x = (const float*)d_in[0];
    float* out = (float*)d_out;
    unsigned* ws = (unsigned*)d_ws;
    const int n = in_sizes[0];          // 100663296
    const int n4 = n >> 2;
    const int nrows = n >> 10;          // 98304 rows of 1024

    (void)hipMemsetAsync(ws, 0, sizeof(unsigned), stream);
    absmax_k<<<2048, 256, 0, stream>>>((const vf4*)x, n4, ws);
    qsm_k<<<nrows / 4, 256, 0, stream>>>(x, out, ws, nrows);
}